// Round 4
// baseline (1759.483 us; speedup 1.0000x reference)
//
#include <hip/hip_runtime.h>

#define FDIM 128
#define NREL 8
#define BM 64
#define ELDS 512
#define SCHUNK 4096

typedef __attribute__((ext_vector_type(8))) short bf16x8;
typedef __attribute__((ext_vector_type(8))) unsigned short u16x8;
typedef __attribute__((ext_vector_type(4))) float f32x4;

__device__ __forceinline__ unsigned short f2bf(float f) {
  unsigned int u = __float_as_uint(f);
  u += 0x7fffu + ((u >> 16) & 1u);   // round-to-nearest-even
  return (unsigned short)(u >> 16);
}
__device__ __forceinline__ float bf2f(unsigned short h) {
  return __uint_as_float(((unsigned int)h) << 16);
}

// ---------------- prep kernels (once; edges are layer-invariant) ----------------

__global__ void zero_u32(unsigned int* __restrict__ p, long n) {
  long i = (long)blockIdx.x * blockDim.x + threadIdx.x;
  long s = (long)gridDim.x * blockDim.x;
  for (; i < n; i += s) p[i] = 0u;
}

__global__ void cvt_bf16_k(const float4* __restrict__ in, ushort4* __restrict__ out, long n4) {
  long i = (long)blockIdx.x * blockDim.x + threadIdx.x;
  long s = (long)gridDim.x * blockDim.x;
  for (; i < n4; i += s) {
    float4 v = in[i];
    out[i] = make_ushort4(f2bf(v.x), f2bf(v.y), f2bf(v.z), f2bf(v.w));
  }
}

__global__ void hist_k(const int* __restrict__ dst, const int* __restrict__ et,
                       int E, int* __restrict__ cnt, int N) {
  int e = blockIdx.x * 256 + threadIdx.x;
  if (e < E) atomicAdd(&cnt[et[e] * N + dst[e]], 1);
}

__global__ void scan_partial(const int* __restrict__ cnt, int n, int* __restrict__ sums) {
  __shared__ int red[256];
  int base = blockIdx.x * SCHUNK;
  int s = 0;
  for (int i = threadIdx.x; i < SCHUNK; i += 256) {
    int j = base + i;
    s += (j < n) ? cnt[j] : 0;
  }
  red[threadIdx.x] = s;
  __syncthreads();
  for (int o = 128; o > 0; o >>= 1) {
    if (threadIdx.x < o) red[threadIdx.x] += red[threadIdx.x + o];
    __syncthreads();
  }
  if (threadIdx.x == 0) sums[blockIdx.x] = red[0];
}

__global__ void scan_sums(int* __restrict__ sums, int nb) {
  __shared__ int tmp[256];
  int t = threadIdx.x;
  int v = (t < nb) ? sums[t] : 0;
  tmp[t] = v;
  __syncthreads();
  for (int o = 1; o < 256; o <<= 1) {
    int u = (t >= o) ? tmp[t - o] : 0;
    __syncthreads();
    tmp[t] += u;
    __syncthreads();
  }
  if (t < nb) sums[t] = tmp[t] - v;  // exclusive
}

__global__ void scan_final(const int* __restrict__ cnt, int n,
                           const int* __restrict__ sums, int* __restrict__ off) {
  __shared__ int red[256];
  int t = threadIdx.x;
  int base = blockIdx.x * SCHUNK;
  int loc[16];
  int s = 0;
#pragma unroll
  for (int i = 0; i < 16; ++i) {
    int j = base + t * 16 + i;
    int v = (j < n) ? cnt[j] : 0;
    loc[i] = s;
    s += v;
  }
  red[t] = s;
  __syncthreads();
  int mine = s;
  for (int o = 1; o < 256; o <<= 1) {
    int u = (t >= o) ? red[t - o] : 0;
    __syncthreads();
    red[t] += u;
    __syncthreads();
  }
  int tp = red[t] - mine;
  int bb = sums[blockIdx.x];
#pragma unroll
  for (int i = 0; i < 16; ++i) {
    int j = base + t * 16 + i;
    if (j < n) off[j] = bb + tp + loc[i];
  }
}

__global__ void sort_k(const int* __restrict__ src, const int* __restrict__ dst,
                       const int* __restrict__ et, int E, int* __restrict__ cur,
                       int2* __restrict__ ssd, int N) {
  int e = blockIdx.x * 256 + threadIdx.x;
  if (e < E) {
    int d = dst[e];
    int key = et[e] * N + d;
    int p = atomicAdd(&cur[key], 1);
    ssd[p] = make_int2(src[e], d);
  }
}

// transpose {root, W0..W7} per layer into bf16 [j][k]; 27 blocks
__global__ void wtrans_k(const float* __restrict__ r1, const float* __restrict__ w1,
                         const float* __restrict__ r2, const float* __restrict__ w2,
                         const float* __restrict__ r3, const float* __restrict__ w3,
                         unsigned short* __restrict__ Wt) {
  int b = blockIdx.x;
  int L = b / 9, s = b % 9;
  const float* root = (L == 0) ? r1 : (L == 1) ? r2 : r3;
  const float* W = (L == 0) ? w1 : (L == 1) ? w2 : w3;
  const float* src = (s == 0) ? root : W + (size_t)(s - 1) * FDIM * FDIM;
  unsigned short* out = Wt + (size_t)b * FDIM * FDIM;
  for (int i = threadIdx.x; i < FDIM * FDIM; i += 256) {
    int j = i >> 7, k = i & 127;
    out[i] = f2bf(src[k * FDIM + j]);
  }
}

// ---------------- fused layer: out = relu(bias + in@root + sum_r mean_r(in)@W_r) ----
// in: bf16 [N][128]. One block = 64 output rows.
// Root: a-frags straight from global. Relations: contiguous sorted-edge slice
// staged coalesced into LDS, then TASK-parallel gathers (task = edge x 16B chunk,
// 4-deep batches => ~3k independent loads in flight/block) accumulated into a
// swizzled fp32 LDS tile via bank-rotated ds atomics. MFMA 16x16x32 bf16.
__global__ __launch_bounds__(256) void fused_layer(
    const unsigned short* __restrict__ in, const int2* __restrict__ ssd,
    const int* __restrict__ off, const unsigned short* __restrict__ Wt,
    const float* __restrict__ bias, void* __restrict__ outv, int N, int out_fp32) {
  __shared__ __align__(16) float accs[BM * FDIM];           // 32 KB fp32 A accumulate
  __shared__ __align__(16) unsigned short Bs[FDIM * FDIM];  // 32 KB bf16 W tile
  __shared__ int2 eL[ELDS];                                 // 4 KB edge slice
  __shared__ float scl[BM];

  const int tid = threadIdx.x;
  const int wave = tid >> 6, lane = tid & 63;
  const int l16 = lane & 15, lq = lane >> 4;
  const int row0 = blockIdx.x * BM;
  const int nrows = min(BM, N - row0);

  f32x4 pacc[8];
#pragma unroll
  for (int n = 0; n < 8; ++n) pacc[n] = (f32x4){0.f, 0.f, 0.f, 0.f};

  // ---- issue root a-frag loads (global, independent) ----
  const int arow = wave * 16 + l16;
  u16x8 ar[4] = {};
  if (row0 + arow < N) {
    const u16x8* rp = (const u16x8*)(in + (size_t)(row0 + arow) * FDIM);
#pragma unroll
    for (int kk = 0; kk < 4; ++kk) ar[kk] = rp[kk * 4 + lq];
  }

  // ---- stage Bs for source 0 (root), prefetch source 1 ----
  u16x8 breg[8];
  {
    const u16x8* g = (const u16x8*)Wt;
#pragma unroll
    for (int i = 0; i < 8; ++i) breg[i] = g[tid + 256 * i];
#pragma unroll
    for (int i = 0; i < 8; ++i) {
      int u = tid + 256 * i;
      int r = u >> 4, kb = u & 15;
      ((u16x8*)Bs)[(r << 4) | (kb ^ (r & 7))] = breg[i];
    }
    const u16x8* g1 = (const u16x8*)(Wt + FDIM * FDIM);
#pragma unroll
    for (int i = 0; i < 8; ++i) breg[i] = g1[tid + 256 * i];
  }
  __syncthreads();

  // ---- root MFMA ----
#pragma unroll
  for (int kk = 0; kk < 4; ++kk) {
    bf16x8 a = (bf16x8)ar[kk];
#pragma unroll
    for (int n = 0; n < 8; ++n) {
      int br = n * 16 + l16;
      bf16x8 b = ((const bf16x8*)Bs)[(br << 4) | ((kk * 4 + lq) ^ (br & 7))];
      pacc[n] = __builtin_amdgcn_mfma_f32_16x16x32_bf16(a, b, pacc[n], 0, 0, 0);
    }
  }

  // ---- relations ----
  for (int s = 1; s <= NREL; ++s) {
    __syncthreads();  // prev MFMA's Bs reads done
#pragma unroll
    for (int i = 0; i < 8; ++i) {
      int u = tid + 256 * i;
      int r = u >> 4, kb = u & 15;
      ((u16x8*)Bs)[(r << 4) | (kb ^ (r & 7))] = breg[i];
    }
#pragma unroll
    for (int i = 0; i < 8; ++i)
      ((float4*)accs)[tid + 256 * i] = make_float4(0.f, 0.f, 0.f, 0.f);
    if (s < NREL) {
      const u16x8* g = (const u16x8*)(Wt + (size_t)(s + 1) * FDIM * FDIM);
#pragma unroll
      for (int i = 0; i < 8; ++i) breg[i] = g[tid + 256 * i];
    }
    const int key0 = (s - 1) * N + row0;
    if (tid < BM) {
      float sc = 0.f;
      if (tid < nrows) {
        int c = off[key0 + tid + 1] - off[key0 + tid];
        sc = (c > 0) ? 1.0f / (float)c : 0.f;
      }
      scl[tid] = sc;
    }
    int ebase = off[key0];
    const int eendAll = off[key0 + nrows];
    __syncthreads();  // Bs + zeroed accs + scl visible

    while (ebase < eendAll) {
      int ne = min(eendAll - ebase, ELDS);
      for (int i = tid; i < ne; i += 256) eL[i] = ssd[ebase + i];
      __syncthreads();
      const int ntask = ne << 4;  // task = (edge, 16-bf16 chunk)
      for (int bt = 0; bt < ntask; bt += 1024) {
        u16x8 vv[4];
        int lrr[4], unn[4], eii[4];
        bool ok[4];
#pragma unroll
        for (int j = 0; j < 4; ++j) {
          int t = bt + j * 256 + tid;
          ok[j] = (t < ntask);
          if (ok[j]) {
            int ei = t >> 4, un = t & 15;
            int2 ed = eL[ei];
            vv[j] = ((const u16x8*)(in + (size_t)ed.x * FDIM))[un];
            lrr[j] = ed.y - row0;
            unn[j] = un;
            eii[j] = ei;
          }
        }
#pragma unroll
        for (int j = 0; j < 4; ++j) {
          if (!ok[j]) continue;
          const int un = unn[j], lr = lrr[j], sw = lr & 7;
          float* rowp = &accs[lr << 7];
          float vals[8];
          int fidx[8];
#pragma unroll
          for (int i = 0; i < 8; ++i) {
            vals[i] = bf2f((unsigned short)vv[j][i]);
            fidx[i] = (((2 * un + (i >> 2)) ^ sw) << 2) + (i & 3);
          }
          // bank-rotated issue order: lanes cover all 32 banks (<=2-way)
          const int start = ((un >> 2) | ((eii[j] & 1) << 2)) & 7;
#pragma unroll
          for (int m = 0; m < 8; ++m) {
            int i = (m + start) & 7;
            atomicAdd(rowp + fidx[i], vals[i]);
          }
        }
      }
      ebase += ne;
      __syncthreads();  // atomics complete (before eL reuse / MFMA)
    }

    // ---- MFMA for this relation ----
    const float sc = scl[arow];
#pragma unroll
    for (int kk = 0; kk < 4; ++kk) {
      int cu = (kk * 4 + lq) * 2;
      f32x4 f0 = ((const f32x4*)accs)[(arow << 5) | (cu ^ (arow & 7))];
      f32x4 f1 = ((const f32x4*)accs)[(arow << 5) | ((cu + 1) ^ (arow & 7))];
      bf16x8 a;
      a[0] = (short)f2bf(f0[0] * sc); a[1] = (short)f2bf(f0[1] * sc);
      a[2] = (short)f2bf(f0[2] * sc); a[3] = (short)f2bf(f0[3] * sc);
      a[4] = (short)f2bf(f1[0] * sc); a[5] = (short)f2bf(f1[1] * sc);
      a[6] = (short)f2bf(f1[2] * sc); a[7] = (short)f2bf(f1[3] * sc);
#pragma unroll
      for (int n = 0; n < 8; ++n) {
        int br = n * 16 + l16;
        bf16x8 b = ((const bf16x8*)Bs)[(br << 4) | ((kk * 4 + lq) ^ (br & 7))];
        pacc[n] = __builtin_amdgcn_mfma_f32_16x16x32_bf16(a, b, pacc[n], 0, 0, 0);
      }
    }
  }

  // ---- epilogue: D layout col=lane&15, row=(lane>>4)*4+reg; bias + relu ----
  if (out_fp32) {
    float* out = (float*)outv;
#pragma unroll
    for (int n = 0; n < 8; ++n) {
      int col = (n << 4) | l16;
      float bv = bias[col];
#pragma unroll
      for (int rr = 0; rr < 4; ++rr) {
        int row = wave * 16 + lq * 4 + rr;
        if (row0 + row < N)
          out[(size_t)(row0 + row) * FDIM + col] = fmaxf(pacc[n][rr] + bv, 0.f);
      }
    }
  } else {
    unsigned short* out = (unsigned short*)outv;
#pragma unroll
    for (int n = 0; n < 8; ++n) {
      int col = (n << 4) | l16;
      float bv = bias[col];
#pragma unroll
      for (int rr = 0; rr < 4; ++rr) {
        int row = wave * 16 + lq * 4 + rr;
        if (row0 + row < N)
          out[(size_t)(row0 + row) * FDIM + col] = f2bf(fmaxf(pacc[n][rr] + bv, 0.f));
      }
    }
  }
}

// ---------------- host ----------------

extern "C" void kernel_launch(void* const* d_in, const int* in_sizes, int n_in,
                              void* d_out, int out_size, void* d_ws, size_t ws_size,
                              hipStream_t stream) {
  const float* x = (const float*)d_in[0];
  const int* ei = (const int*)d_in[1];
  const int* et = (const int*)d_in[2];
  const float* W[3]    = {(const float*)d_in[3], (const float*)d_in[6], (const float*)d_in[9]};
  const float* root[3] = {(const float*)d_in[4], (const float*)d_in[7], (const float*)d_in[10]};
  const float* bias[3] = {(const float*)d_in[5], (const float*)d_in[8], (const float*)d_in[11]};

  const int N = in_sizes[0] / FDIM;
  const int E = in_sizes[1] / 2;
  const int* src = ei;
  const int* dst = ei + E;
  const int NK = NREL * N;

  char* w = (char*)d_ws;
  size_t pos = 0;
  auto carve = [&](size_t bytes) -> void* {
    pos = (pos + 255) & ~(size_t)255;
    void* p = w + pos;
    pos += bytes;
    return p;
  };
  int* cnt = (int*)carve(sizeof(int) * (NK + 1));
  int* off = (int*)carve(sizeof(int) * (NK + 1));
  int* cur = (int*)carve(sizeof(int) * (NK + 1));
  int* sums = (int*)carve(sizeof(int) * 512);
  int2* ssd = (int2*)carve(sizeof(int2) * E);
  unsigned short* Wt = (unsigned short*)carve(sizeof(unsigned short) * 27 * FDIM * FDIM);
  unsigned short* xb = (unsigned short*)carve(sizeof(unsigned short) * (size_t)N * FDIM);
  unsigned short* h1 = (unsigned short*)carve(sizeof(unsigned short) * (size_t)N * FDIM);
  unsigned short* h2 = (unsigned short*)carve(sizeof(unsigned short) * (size_t)N * FDIM);

  // ---- one-time prep: x->bf16, counting sort by key = rel*N + dst, W transpose ----
  cvt_bf16_k<<<2048, 256, 0, stream>>>((const float4*)x, (ushort4*)xb, (long)N * FDIM / 4);
  zero_u32<<<1024, 256, 0, stream>>>((unsigned int*)cnt, NK + 1);
  hist_k<<<(E + 255) / 256, 256, 0, stream>>>(dst, et, E, cnt, N);
  const int n_scan = NK + 1;
  const int nchunk = (n_scan + SCHUNK - 1) / SCHUNK;
  scan_partial<<<nchunk, 256, 0, stream>>>(cnt, n_scan, sums);
  scan_sums<<<1, 256, 0, stream>>>(sums, nchunk);
  scan_final<<<nchunk, 256, 0, stream>>>(cnt, n_scan, sums, off);
  hipMemcpyAsync(cur, off, sizeof(int) * NK, hipMemcpyDeviceToDevice, stream);
  sort_k<<<(E + 255) / 256, 256, 0, stream>>>(src, dst, et, E, cur, ssd, N);
  wtrans_k<<<27, 256, 0, stream>>>(root[0], W[0], root[1], W[1], root[2], W[2], Wt);

  // ---- 3 fused layers (bf16 -> bf16 -> bf16 -> fp32) ----
  const int NB = (N + BM - 1) / BM;
  fused_layer<<<NB, 256, 0, stream>>>(xb, ssd, off, Wt, bias[0], h1, N, 0);
  fused_layer<<<NB, 256, 0, stream>>>(h1, ssd, off, Wt + (size_t)9 * FDIM * FDIM,
                                      bias[1], h2, N, 0);
  fused_layer<<<NB, 256, 0, stream>>>(h2, ssd, off, Wt + (size_t)18 * FDIM * FDIM,
                                      bias[2], d_out, N, 1);
}